// Round 8
// baseline (494.815 us; speedup 1.0000x reference)
//
#include <hip/hip_runtime.h>

typedef __bf16 bf16;
typedef __bf16 bf16x8 __attribute__((ext_vector_type(8)));
typedef _Float16 f16;
typedef _Float16 f16x8 __attribute__((ext_vector_type(8)));
typedef float f32x4 __attribute__((ext_vector_type(4)));

#define SCALE_Q 0.17677669529663687f
#define KSCALE 64.0f
#define KSCALE_INV 0.015625f

// ======================= weight prep: wqkv^T bf16; wout^T fp16 hi/lo (x64) =======================
__global__ __launch_bounds__(256) void k_prep_w(const float* __restrict__ wqkv,
                                                const float* __restrict__ wout,
                                                bf16* __restrict__ wqkv_t,
                                                f16* __restrict__ wout_h,
                                                f16* __restrict__ wout_l) {
    int n = blockIdx.x, k = threadIdx.x;
    if (n < 768) {
        wqkv_t[n * 256 + k] = (bf16)wqkv[k * 768 + n];
    } else {
        float f = wout[k * 256 + (n - 768)] * KSCALE;
        f16 hi = (f16)f;
        wout_h[(n - 768) * 256 + k] = hi;
        wout_l[(n - 768) * 256 + k] = (f16)(f - (float)hi);
    }
}

// ======================= kt build (permute conv_w); LDS stride 145 => conflict-free transpose read =======================
__global__ __launch_bounds__(256) void k_build_kt(const float* __restrict__ conv_w,
                                                  bf16* __restrict__ kt) {
    __shared__ float lds[16 * 145];
    int w = blockIdx.x >> 8, co = blockIdx.x & 255;
    const float* src = conv_w + (size_t)(w * 256 + co) * 2304;
    for (int i = threadIdx.x; i < 2304; i += 256) {
        int m = i / 144, tt = i - m * 144;
        lds[m * 145 + tt] = src[i];
    }
    __syncthreads();
    int b = co >> 4, c0 = (co & 15) << 4;
    size_t rbase = (size_t)(b * 16 + w) * 144;
    for (int i = threadIdx.x; i < 2304; i += 256) {
        int t = i >> 4, m = i & 15;
        kt[(rbase + t) * 256 + c0 + m] = (bf16)lds[m * 145 + t];
    }
}

// ======================= async staging primitives =======================
// LDS dest is linear (wave-uniform base + lane*16); the XOR part-swizzle
// LDS(row, s) = global(row, s ^ ((row>>1)&3)) is applied to the per-lane
// GLOBAL source address (involution => same map both sides).
typedef const __attribute__((address_space(1))) unsigned int* gas_t;
typedef __attribute__((address_space(3))) unsigned int* las_t;

__device__ __forceinline__ void async_copy16(const void* g, void* l) {
    __builtin_amdgcn_global_load_lds((gas_t)g, (las_t)l, 16, 0, 0);
}

// ======================= MFMA fragment compute (swizzle f(r) = (r>>1)&3) =======================
__device__ __forceinline__ void mfma_tile_bf16(const bf16* As, const bf16* Bs,
                                               f32x4 acc[4][4]) {
    int lane = threadIdx.x & 63;
    int wave = threadIdx.x >> 6;
    int wm = (wave >> 1) * 64, wn = (wave & 1) * 64;
    int lrow = lane & 15, quad = lane >> 4;
    bf16x8 af[4], bfr[4];
#pragma unroll
    for (int i = 0; i < 4; i++) {
        int r = wm + i * 16 + lrow;
        af[i] = *(const bf16x8*)(As + r * 32 + ((quad ^ ((r >> 1) & 3)) << 3));
        int n = wn + i * 16 + lrow;
        bfr[i] = *(const bf16x8*)(Bs + n * 32 + ((quad ^ ((n >> 1) & 3)) << 3));
    }
#pragma unroll
    for (int i = 0; i < 4; i++)
#pragma unroll
        for (int j = 0; j < 4; j++)
            acc[i][j] = __builtin_amdgcn_mfma_f32_16x16x32_bf16(af[i], bfr[j], acc[i][j], 0, 0, 0);
}

// dual-B variant (64x64 wave tile): load A fragments once, run hi and lo products
__device__ __forceinline__ void mfma_tile_f16_dual(const f16* As, const f16* Bhs,
                                                   const f16* Bls, f32x4 acc[4][4]) {
    int lane = threadIdx.x & 63;
    int wave = threadIdx.x >> 6;
    int wm = (wave >> 1) * 64, wn = (wave & 1) * 64;
    int lrow = lane & 15, quad = lane >> 4;
    f16x8 af[4], bh[4], bl[4];
#pragma unroll
    for (int i = 0; i < 4; i++) {
        int r = wm + i * 16 + lrow;
        af[i] = *(const f16x8*)(As + r * 32 + ((quad ^ ((r >> 1) & 3)) << 3));
        int n = wn + i * 16 + lrow;
        bh[i] = *(const f16x8*)(Bhs + n * 32 + ((quad ^ ((n >> 1) & 3)) << 3));
        bl[i] = *(const f16x8*)(Bls + n * 32 + ((quad ^ ((n >> 1) & 3)) << 3));
    }
#pragma unroll
    for (int i = 0; i < 4; i++)
#pragma unroll
        for (int j = 0; j < 4; j++) {
            acc[i][j] = __builtin_amdgcn_mfma_f32_16x16x32_f16(af[i], bh[j], acc[i][j], 0, 0, 0);
            acc[i][j] = __builtin_amdgcn_mfma_f32_16x16x32_f16(af[i], bl[j], acc[i][j], 0, 0, 0);
        }
}

// 8-wave dual-B variant (128x64 wave tile, waves as 2 rows x 4 cols over 256x256 block)
__device__ __forceinline__ void mfma_tile_f16_dual8b(const f16* As, const f16* Bhs,
                                                     const f16* Bls, f32x4 acc[8][4]) {
    int lane = threadIdx.x & 63;
    int wave = threadIdx.x >> 6;                  // 0..7
    int wm = (wave >> 2) * 128, wn = (wave & 3) * 64;
    int lrow = lane & 15, quad = lane >> 4;
    f16x8 af[8], bh[4], bl[4];
#pragma unroll
    for (int i = 0; i < 8; i++) {
        int r = wm + i * 16 + lrow;
        af[i] = *(const f16x8*)(As + r * 32 + ((quad ^ ((r >> 1) & 3)) << 3));
    }
#pragma unroll
    for (int j = 0; j < 4; j++) {
        int n = wn + j * 16 + lrow;
        bh[j] = *(const f16x8*)(Bhs + n * 32 + ((quad ^ ((n >> 1) & 3)) << 3));
        bl[j] = *(const f16x8*)(Bls + n * 32 + ((quad ^ ((n >> 1) & 3)) << 3));
    }
#pragma unroll
    for (int i = 0; i < 8; i++)
#pragma unroll
        for (int j = 0; j < 4; j++) {
            acc[i][j] = __builtin_amdgcn_mfma_f32_16x16x32_f16(af[i], bh[j], acc[i][j], 0, 0, 0);
            acc[i][j] = __builtin_amdgcn_mfma_f32_16x16x32_f16(af[i], bl[j], acc[i][j], 0, 0, 0);
        }
}

// ======================= qkv GEMM (bf16, dbuf + counted vmcnt) =======================
__global__ __launch_bounds__(256) void k_gemm_qkv(const bf16* __restrict__ A,
                                                  const bf16* __restrict__ Bt,
                                                  const float* __restrict__ bias,
                                                  bf16* __restrict__ outb,
                                                  int N, int K) {
    __shared__ __align__(16) bf16 As[2][128 * 32];
    __shared__ __align__(16) bf16 Bs[2][128 * 32];
    int m0 = blockIdx.y * 128, n0 = blockIdx.x * 128;
    int t = threadIdx.x, wave = t >> 6, lane = t & 63;
    int chunk0 = wave * 2, chunk1 = chunk0 + 1;
    int row0 = chunk0 * 16 + (lane >> 2), row1 = row0 + 16;
    int sw = ((lane & 3) ^ ((row0 >> 1) & 3)) << 3;   // (row1>>1)&3 == (row0>>1)&3
    const unsigned short* Ag = (const unsigned short*)A;
    const unsigned short* Bg = (const unsigned short*)Bt;
    size_t a0 = (size_t)(m0 + row0) * K + sw, a1 = (size_t)(m0 + row1) * K + sw;
    size_t b0 = (size_t)(n0 + row0) * K + sw, b1 = (size_t)(n0 + row1) * K + sw;
    f32x4 acc[4][4] = {};
#define STG_QKV(cur, k0)                                        \
    async_copy16(Ag + a0 + (k0), &As[cur][chunk0 * 512]);       \
    async_copy16(Ag + a1 + (k0), &As[cur][chunk1 * 512]);       \
    async_copy16(Bg + b0 + (k0), &Bs[cur][chunk0 * 512]);       \
    async_copy16(Bg + b1 + (k0), &Bs[cur][chunk1 * 512]);
    STG_QKV(0, 0);
    int cur = 0, NT = K >> 5;
#pragma unroll 1
    for (int it = 0; it < NT; it++) {
        if (it < NT - 1) {
            STG_QKV(cur ^ 1, (it + 1) << 5);
            asm volatile("s_waitcnt vmcnt(4)" ::: "memory");
        } else {
            asm volatile("s_waitcnt vmcnt(0)" ::: "memory");
        }
        __builtin_amdgcn_s_barrier();
        mfma_tile_bf16(As[cur], Bs[cur], acc);
        asm volatile("s_waitcnt lgkmcnt(0)" ::: "memory");
        __builtin_amdgcn_s_barrier();
        cur ^= 1;
    }
#undef STG_QKV
    int wm = (wave >> 1) * 64, wn = (wave & 1) * 64;
    int lrow = lane & 15, quad = lane >> 4;
#pragma unroll
    for (int i = 0; i < 4; i++)
#pragma unroll
        for (int j = 0; j < 4; j++) {
            int col = n0 + wn + j * 16 + lrow;
            float bv = bias[col];
#pragma unroll
            for (int rr = 0; rr < 4; rr++) {
                int row = m0 + wm + i * 16 + quad * 4 + rr;
                float v = acc[i][j][rr] + bv;
                if (col < 256) v *= SCALE_Q;
                outb[(size_t)row * N + col] = (bf16)v;
            }
        }
}

// ======================= out-proj GEMM: A fp16 single, B fp16 hi/lo (x64) =======================
__global__ __launch_bounds__(256) void k_gemm_split2(const f16* __restrict__ Ag_,
                                                     const f16* __restrict__ Bhg,
                                                     const f16* __restrict__ Blg,
                                                     const float* __restrict__ bias,
                                                     float* __restrict__ outf,
                                                     int N, int K) {
    __shared__ __align__(16) f16 As[2][128 * 32];
    __shared__ __align__(16) f16 Bh[2][128 * 32];
    __shared__ __align__(16) f16 Bl[2][128 * 32];
    int m0 = blockIdx.y * 128, n0 = blockIdx.x * 128;
    int t = threadIdx.x, wave = t >> 6, lane = t & 63;
    int chunk0 = wave * 2, chunk1 = chunk0 + 1;
    int row0 = chunk0 * 16 + (lane >> 2), row1 = row0 + 16;
    int sw = ((lane & 3) ^ ((row0 >> 1) & 3)) << 3;
    const unsigned short* Au = (const unsigned short*)Ag_;
    const unsigned short* Bhu = (const unsigned short*)Bhg;
    const unsigned short* Blu = (const unsigned short*)Blg;
    size_t a0 = (size_t)(m0 + row0) * K + sw, a1 = (size_t)(m0 + row1) * K + sw;
    size_t b0 = (size_t)(n0 + row0) * K + sw, b1 = (size_t)(n0 + row1) * K + sw;
    f32x4 acc[4][4] = {};
#define STG_SP2(cur, k0)                                        \
    async_copy16(Au + a0 + (k0), &As[cur][chunk0 * 512]);       \
    async_copy16(Au + a1 + (k0), &As[cur][chunk1 * 512]);       \
    async_copy16(Bhu + b0 + (k0), &Bh[cur][chunk0 * 512]);      \
    async_copy16(Bhu + b1 + (k0), &Bh[cur][chunk1 * 512]);      \
    async_copy16(Blu + b0 + (k0), &Bl[cur][chunk0 * 512]);      \
    async_copy16(Blu + b1 + (k0), &Bl[cur][chunk1 * 512]);
    STG_SP2(0, 0);
    int cur = 0, NT = K >> 5;
#pragma unroll 1
    for (int it = 0; it < NT; it++) {
        if (it < NT - 1) {
            STG_SP2(cur ^ 1, (it + 1) << 5);
            asm volatile("s_waitcnt vmcnt(6)" ::: "memory");
        } else {
            asm volatile("s_waitcnt vmcnt(0)" ::: "memory");
        }
        __builtin_amdgcn_s_barrier();
        mfma_tile_f16_dual(As[cur], Bh[cur], Bl[cur], acc);
        asm volatile("s_waitcnt lgkmcnt(0)" ::: "memory");
        __builtin_amdgcn_s_barrier();
        cur ^= 1;
    }
#undef STG_SP2
    int wm = (wave >> 1) * 64, wn = (wave & 1) * 64;
    int lrow = lane & 15, quad = lane >> 4;
#pragma unroll
    for (int i = 0; i < 4; i++)
#pragma unroll
        for (int j = 0; j < 4; j++) {
            int col = n0 + wn + j * 16 + lrow;
            float bv = bias[col];
#pragma unroll
            for (int rr = 0; rr < 4; rr++) {
                int row = m0 + wm + i * 16 + quad * 4 + rr;
                outf[(size_t)row * N + col] = acc[i][j][rr] * KSCALE_INV + bv;
            }
        }
}

// ======================= attention: MFMA flash-style per (d,h) block =======================
__global__ __launch_bounds__(256) void k_attn(const bf16* __restrict__ qkv,
                                              f16* __restrict__ o16) {
    __shared__ bf16 Qs[144 * 32];
    __shared__ bf16 Ks[144 * 32];
    __shared__ f16 Vt[32 * 160];
    __shared__ f16 Ps[4 * 16 * 168];
    int d = blockIdx.x >> 3, h = blockIdx.x & 7;
    const bf16* base = qkv + (size_t)d * 144 * 768 + h * 32;
    int t = threadIdx.x;

    for (int i = t; i < 512; i += 256) Vt[(i >> 4) * 160 + 144 + (i & 15)] = (f16)0.f;
    for (int i = t; i < 576; i += 256) {     // 144 rows * 4 parts
        int row = i >> 2, part = i & 3;
        const bf16* rp = base + (size_t)row * 768;
        uint4 vq = *(const uint4*)(rp + (part << 3));
        uint4 vk = *(const uint4*)(rp + 256 + (part << 3));
        int sw = ((part ^ (row & 3)) << 3);
        *(uint4*)(Qs + row * 32 + sw) = vq;
        *(uint4*)(Ks + row * 32 + sw) = vk;
        bf16x8 v8 = *(const bf16x8*)(rp + 512 + (part << 3));
#pragma unroll
        for (int j = 0; j < 8; j++) Vt[(part * 8 + j) * 160 + row] = (f16)(float)v8[j];
    }
    __syncthreads();

    int wave = t >> 6, lane = t & 63;
    int lrow = lane & 15, quad = lane >> 4;
    f16* Pw = Ps + wave * 16 * 168;
    for (int i = lane; i < 256; i += 64) Pw[(i >> 4) * 168 + 144 + (i & 15)] = (f16)0.f;

    bf16x8 kf[9];
#pragma unroll
    for (int nt = 0; nt < 9; nt++) {
        int r = nt * 16 + lrow;
        kf[nt] = *(const bf16x8*)(Ks + r * 32 + ((quad ^ (r & 3)) << 3));
    }

    for (int mt = wave; mt < 9; mt += 4) {
        int qr = mt * 16 + lrow;
        bf16x8 qf = *(const bf16x8*)(Qs + qr * 32 + ((quad ^ (qr & 3)) << 3));
        f32x4 s[9];
#pragma unroll
        for (int nt = 0; nt < 9; nt++) {
            f32x4 z = {0.f, 0.f, 0.f, 0.f};
            s[nt] = __builtin_amdgcn_mfma_f32_16x16x32_bf16(qf, kf[nt], z, 0, 0, 0);
        }
        f32x4 mx = s[0];
#pragma unroll
        for (int nt = 1; nt < 9; nt++)
#pragma unroll
            for (int c = 0; c < 4; c++) mx[c] = fmaxf(mx[c], s[nt][c]);
#pragma unroll
        for (int off = 1; off < 16; off <<= 1)
#pragma unroll
            for (int c = 0; c < 4; c++) mx[c] = fmaxf(mx[c], __shfl_xor(mx[c], off));
        f32x4 sm = {0.f, 0.f, 0.f, 0.f};
#pragma unroll
        for (int nt = 0; nt < 9; nt++)
#pragma unroll
            for (int c = 0; c < 4; c++) {
                float e = __expf(s[nt][c] - mx[c]);
                s[nt][c] = e;
                sm[c] += e;
            }
#pragma unroll
        for (int off = 1; off < 16; off <<= 1)
#pragma unroll
            for (int c = 0; c < 4; c++) sm[c] += __shfl_xor(sm[c], off);
        f32x4 inv;
#pragma unroll
        for (int c = 0; c < 4; c++) inv[c] = 1.f / sm[c];
#pragma unroll
        for (int nt = 0; nt < 9; nt++)
#pragma unroll
            for (int c = 0; c < 4; c++)
                Pw[(quad * 4 + c) * 168 + nt * 16 + lrow] = (f16)(s[nt][c] * inv[c]);

        f32x4 o0 = {0.f, 0.f, 0.f, 0.f}, o1 = {0.f, 0.f, 0.f, 0.f};
#pragma unroll
        for (int kt = 0; kt < 5; kt++) {
            f16x8 pf = *(const f16x8*)(Pw + lrow * 168 + kt * 32 + quad * 8);
            f16x8 v0 = *(const f16x8*)(Vt + lrow * 160 + kt * 32 + quad * 8);
            f16x8 v1 = *(const f16x8*)(Vt + (16 + lrow) * 160 + kt * 32 + quad * 8);
            o0 = __builtin_amdgcn_mfma_f32_16x16x32_f16(pf, v0, o0, 0, 0, 0);
            o1 = __builtin_amdgcn_mfma_f32_16x16x32_f16(pf, v1, o1, 0, 0, 0);
        }
        size_t ro = ((size_t)d * 144 + mt * 16) * 256 + h * 32;
#pragma unroll
        for (int c = 0; c < 4; c++) {
            size_t rr = ro + (size_t)(quad * 4 + c) * 256;
            o16[rr + lrow] = (f16)o0[c];
            o16[rr + 16 + lrow] = (f16)o1[c];
        }
    }
}

// ======================= SE gate + scale + pack B^T fp16 hi/lo (x64) for conv =======================
__global__ __launch_bounds__(256) void k_se_scale(const float* __restrict__ kern,
                                                  const float* __restrict__ w1,
                                                  const float* __restrict__ b1,
                                                  const float* __restrict__ w2,
                                                  const float* __restrict__ b2,
                                                  f16* __restrict__ kern_hi,
                                                  f16* __restrict__ kern_lo) {
    __shared__ float pooled[256];
    __shared__ float hbuf[16];
    int w = blockIdx.x >> 8, Co = blockIdx.x & 255;
    int ci = threadIdx.x;
    const float* kb = kern + (size_t)(Co * 16 + w) * 9 * 256;
    float v9[9];
    float pv = 0.f;
#pragma unroll
    for (int k9 = 0; k9 < 9; k9++) { v9[k9] = kb[k9 * 256 + ci]; pv += v9[k9]; }
    pooled[ci] = pv * (1.f / 9.f);
    __syncthreads();
    // hidden layer: 16 groups x 16 lanes, wave-parallel dot + shfl reduce
    {
        int hid = ci >> 4, l16 = ci & 15;
        const float* w1p = w1 + (size_t)(w * 16 + hid) * 256;
        float hs = 0.f;
#pragma unroll
        for (int c = l16; c < 256; c += 16) hs += pooled[c] * w1p[c];
        hs += __shfl_xor(hs, 1);
        hs += __shfl_xor(hs, 2);
        hs += __shfl_xor(hs, 4);
        hs += __shfl_xor(hs, 8);
        if (l16 == 0) hbuf[hid] = fmaxf(hs + b1[w * 16 + hid], 0.f);
    }
    __syncthreads();
    const float* w2p = w2 + (size_t)(w * 256 + ci) * 16;
    float ss = b2[w * 256 + ci];
#pragma unroll
    for (int j = 0; j < 16; j++) ss += hbuf[j] * w2p[j];
    float s = (1.f / (1.f + __expf(-ss))) * KSCALE;
    size_t outo = (size_t)(w * 256 + Co) * 2304;
    f16* khi = kern_hi + outo;
    f16* klo = kern_lo + outo;
#pragma unroll
    for (int k9 = 0; k9 < 9; k9++) {
        float f = v9[k9] * s;
        f16 hi = (f16)f;
        khi[k9 * 256 + ci] = hi;
        klo[k9 * 256 + ci] = (f16)(f - (float)hi);
    }
}

// ======================= zero only the 1-ring halo of xcl (interior fully overwritten by k_fill_xcl) =======================
__global__ __launch_bounds__(256) void k_zero_pad(f16* __restrict__ xcl) {
    int wb = blockIdx.x;          // w*16 + b, 0..255
    f16* base = xcl + (size_t)wb * 18 * 18 * 256;
    int ci = threadIdx.x;
#pragma unroll 1
    for (int i = 0; i < 68; i++) {
        int py, px;
        if (i < 18) { py = 0; px = i; }
        else if (i < 36) { py = 17; px = i - 18; }
        else { int k = i - 36; py = 1 + (k >> 1); px = (k & 1) * 17; }
        base[((size_t)py * 18 + px) * 256 + ci] = (f16)0.f;
    }
}

// ======================= x -> padded channel-last windows, fp16 single =======================
__global__ __launch_bounds__(256) void k_fill_xcl(const float* __restrict__ x,
                                                  f16* __restrict__ xcl) {
    int bx = blockIdx.x;          // b*64 + gy
    int b = bx >> 6, gy = bx & 63;
    int wrow = gy >> 4, py = gy & 15;
    int ci = threadIdx.x;
    const float* xp = x + ((size_t)(b * 256 + ci) * 64 + gy) * 64;
    for (int wx = 0; wx < 4; wx++) {
        int w = wrow * 4 + wx;
        size_t o = (((size_t)(w * 16 + b) * 18 + py + 1) * 18 + 1) * 256 + ci;
#pragma unroll
        for (int px = 0; px < 16; px++)
            xcl[o + (size_t)px * 256] = (f16)xp[wx * 16 + px];
    }
}

// ======================= per-window conv (256x256 block, 8 waves) + fused LN/residual epilogue =======================
// grid = 256 blocks (1/CU), XCD-chunked: XCD c owns windows {2c, 2c+1}.
// Block owns ALL 256 channels of its 256 pixels => LN+residual done in-epilogue; y never hits HBM.
__global__ __launch_bounds__(512, 2) void k_conv_ln(const f16* __restrict__ xcl,
                                                    const f16* __restrict__ kern_hi,
                                                    const f16* __restrict__ kern_lo,
                                                    const float* __restrict__ x,
                                                    const float* __restrict__ g,
                                                    const float* __restrict__ be,
                                                    float* __restrict__ out) {
    __shared__ __align__(16) f16 As[2][256 * 32];
    __shared__ __align__(16) f16 Bh[2][256 * 32];
    __shared__ __align__(16) f16 Bl[2][256 * 32];
    __shared__ float part[256][4][2];
    __shared__ float stats[256][2];
    int f = blockIdx.x;                       // 0..255
    int xcd = f & 7, i8 = f >> 3;             // i8 0..31
    int w = xcd * 2 + (i8 >> 4);              // window 0..15
    int by = i8 & 15;                         // batch
    const unsigned short* xw = (const unsigned short*)(xcl + (size_t)w * 16 * 18 * 18 * 256);
    const unsigned short* Bthu = (const unsigned short*)(kern_hi + (size_t)w * 256 * 2304);
    const unsigned short* Btlu = (const unsigned short*)(kern_lo + (size_t)w * 256 * 2304);
    int t = threadIdx.x, wave = t >> 6, lane = t & 63;
    // row = c*128 + (t>>2); (row>>1)&3 == (t>>3)&3 for both c (128>>1 = 64, &3 = 0)
    int sw = ((t & 3) ^ ((t >> 3) & 3)) << 3;
    size_t aA[2], bB[2];
#pragma unroll
    for (int c = 0; c < 2; c++) {
        int row = c * 128 + (t >> 2);         // pixel index 0..255
        int py = row >> 4, px = row & 15;
        aA[c] = ((size_t)(by * 18 + py) * 18 + px) * 256 + sw;
        bB[c] = (size_t)row * 2304 + sw;      // n-row = row (n0 = 0, BN=256)
    }
    f32x4 acc[8][4] = {};
    // LDS dest (wave-uniform): elem c*4096 + wave*512 (+ lane*8 implicit)
#define STG_CONV(cur, k0)                                                        \
    {                                                                            \
        int k9_ = (k0) >> 8;                                                     \
        int koff_ = ((k9_ / 3) * 18 + (k9_ % 3)) * 256 + ((k0) & 255);           \
        async_copy16(xw + aA[0] + koff_, &As[cur][wave * 512]);                  \
        async_copy16(xw + aA[1] + koff_, &As[cur][4096 + wave * 512]);           \
        async_copy16(Bthu + bB[0] + (k0), &Bh[cur][wave * 512]);                 \
        async_copy16(Bthu + bB[1] + (k0), &Bh[cur][4096 + wave * 512]);          \
        async_copy16(Btlu + bB[0] + (k0), &Bl[cur][wave * 512]);                 \
        async_copy16(Btlu + bB[1] + (k0), &Bl[cur][4096 + wave * 512]);          \
    }
    STG_CONV(0, 0);
    int cur = 0;
#pragma unroll 1
    for (int it = 0; it < 72; it++) {
        if (it < 71) {
            STG_CONV(cur ^ 1, (it + 1) << 5);
            asm volatile("s_waitcnt vmcnt(6)" ::: "memory");
        } else {
            asm volatile("s_waitcnt vmcnt(0)" ::: "memory");
        }
        __builtin_amdgcn_s_barrier();
        mfma_tile_f16_dual8b(As[cur], Bh[cur], Bl[cur], acc);
        asm volatile("s_waitcnt lgkmcnt(0)" ::: "memory");
        __builtin_amdgcn_s_barrier();
        cur ^= 1;
    }
#undef STG_CONV
    // ---- fused LN + residual epilogue ----
    int lrow = lane & 15, quad = lane >> 4;
    int wm = (wave >> 2) * 128, wn = (wave & 3) * 64;
    // per-pixel partial sums over this wave's 64 channels
#pragma unroll
    for (int i = 0; i < 8; i++)
#pragma unroll
        for (int rr = 0; rr < 4; rr++) {
            float s1 = 0.f, s2 = 0.f;
#pragma unroll
            for (int j = 0; j < 4; j++) {
                float v = acc[i][j][rr] * KSCALE_INV;
                s1 += v; s2 += v * v;
            }
            s1 += __shfl_xor(s1, 1); s2 += __shfl_xor(s2, 1);
            s1 += __shfl_xor(s1, 2); s2 += __shfl_xor(s2, 2);
            s1 += __shfl_xor(s1, 4); s2 += __shfl_xor(s2, 4);
            s1 += __shfl_xor(s1, 8); s2 += __shfl_xor(s2, 8);
            if (lrow == 0) {
                int p = wm + i * 16 + quad * 4 + rr;
                part[p][wave & 3][0] = s1;
                part[p][wave & 3][1] = s2;
            }
        }
    __syncthreads();
    if (t < 256) {
        float s1 = part[t][0][0] + part[t][1][0] + part[t][2][0] + part[t][3][0];
        float s2 = part[t][0][1] + part[t][1][1] + part[t][2][1] + part[t][3][1];
        float mean = s1 * (1.f / 256.f);
        float var = s2 * (1.f / 256.f) - mean * mean;
        stats[t][0] = mean;
        stats[t][1] = rsqrtf(var + 1e-5f);
    }
    __syncthreads();
    float gv[4], bev[4];
#pragma unroll
    for (int j = 0; j < 4; j++) {
        int cc = wn + j * 16 + lrow;
        gv[j] = g[cc]; bev[j] = be[cc];
    }
    int gy0 = (w >> 2) * 16, gx0 = (w & 3) * 16;
#pragma unroll
    for (int i = 0; i < 8; i++)
#pragma unroll
        for (int rr = 0; rr < 4; rr++) {
            int p = wm + i * 16 + quad * 4 + rr;
            float mu = stats[p][0], rs = stats[p][1];
            int gy = gy0 + (p >> 4), gx = gx0 + (p & 15);
            size_t base = ((size_t)(by * 256) * 64 + gy) * 64 + gx;
#pragma unroll
            for (int j = 0; j < 4; j++) {
                int cc = wn + j * 16 + lrow;
                float v = acc[i][j][rr] * KSCALE_INV;
                size_t a = base + (size_t)cc * 4096;
                out[a] = (v - mu) * rs * gv[j] + bev[j] + x[a];
            }
        }
}

// ======================= launch =======================
extern "C" void kernel_launch(void* const* d_in, const int* in_sizes, int n_in,
                              void* d_out, int out_size, void* d_ws, size_t ws_size,
                              hipStream_t stream) {
    const float* x      = (const float*)d_in[0];
    const float* conv_w = (const float*)d_in[1];
    const float* wqkv   = (const float*)d_in[2];
    const float* bqkv   = (const float*)d_in[3];
    const float* wout   = (const float*)d_in[4];
    const float* bout   = (const float*)d_in[5];
    const float* se_w1  = (const float*)d_in[6];
    const float* se_b1  = (const float*)d_in[7];
    const float* se_w2  = (const float*)d_in[8];
    const float* se_b2  = (const float*)d_in[9];
    const float* ln_g   = (const float*)d_in[10];
    const float* ln_b   = (const float*)d_in[11];
    float* out = (float*)d_out;

    // ---- workspace layout (lifetime-overlaid) ----
    char* ws = (char*)d_ws;
    bf16*  kt      = (bf16*)(ws + 0);             // 18,874,368  kt -> o16 -> kern_hi
    f16*   o16     = (f16*)(ws + 0);
    f16*   kern_hi = (f16*)(ws + 0);
    f16*   kern_lo = (f16*)(ws + 18874368);       // 18,874,368
    bf16*  wqkv_t  = (bf16*)(ws + 37748736);      //    393,216
    f16*   wout_h  = (f16*)(ws + 38141952);       //    131,072
    f16*   wout_l  = (f16*)(ws + 38273024);       //    131,072
    f16*   xcl     = (f16*)(ws + 38404096);       // 42,467,328
    bf16*  qkv     = (bf16*)(ws + 80871424);      // 56,623,104  qkv -> kern_f
    float* kern_f  = (float*)(ws + 80871424);     // 37,748,736

    k_prep_w<<<1024, 256, 0, stream>>>(wqkv, wout, wqkv_t, wout_h, wout_l);
    k_build_kt<<<4096, 256, 0, stream>>>(conv_w, kt);
    k_gemm_qkv<<<dim3(6, 288), 256, 0, stream>>>(kt, wqkv_t, bqkv, qkv, 768, 256);
    k_attn<<<2048, 256, 0, stream>>>(qkv, o16);
    k_gemm_split2<<<dim3(2, 288), 256, 0, stream>>>(o16, wout_h, wout_l, bout, kern_f, 256, 256);
    k_se_scale<<<4096, 256, 0, stream>>>(kern_f, se_w1, se_b1, se_w2, se_b2, kern_hi, kern_lo);
    k_zero_pad<<<256, 256, 0, stream>>>(xcl);
    k_fill_xcl<<<1024, 256, 0, stream>>>(x, xcl);
    k_conv_ln<<<256, 512, 0, stream>>>(xcl, kern_hi, kern_lo, x, ln_g, ln_b, out);
}

// Round 9
// 471.053 us; speedup vs baseline: 1.0504x; 1.0504x over previous
//
#include <hip/hip_runtime.h>

typedef __bf16 bf16;
typedef __bf16 bf16x8 __attribute__((ext_vector_type(8)));
typedef _Float16 f16;
typedef _Float16 f16x8 __attribute__((ext_vector_type(8)));
typedef float f32x4 __attribute__((ext_vector_type(4)));

#define SCALE_Q 0.17677669529663687f
#define KSCALE 64.0f
#define KSCALE_INV 0.015625f

// ======================= kt build (permute conv_w) + fused weight prep =======================
// blocks [0,4096): conv_w permute via LDS stride-145 (conflict-free transpose read)
// blocks [4096,5120): wqkv^T bf16; wout^T fp16 hi/lo (x64)
__global__ __launch_bounds__(256) void k_build_kt(const float* __restrict__ conv_w,
                                                  bf16* __restrict__ kt,
                                                  const float* __restrict__ wqkv,
                                                  const float* __restrict__ wout,
                                                  bf16* __restrict__ wqkv_t,
                                                  f16* __restrict__ wout_h,
                                                  f16* __restrict__ wout_l) {
    if (blockIdx.x >= 4096) {
        int n = blockIdx.x - 4096, k = threadIdx.x;
        if (n < 768) {
            wqkv_t[n * 256 + k] = (bf16)wqkv[k * 768 + n];
        } else {
            float f = wout[k * 256 + (n - 768)] * KSCALE;
            f16 hi = (f16)f;
            wout_h[(n - 768) * 256 + k] = hi;
            wout_l[(n - 768) * 256 + k] = (f16)(f - (float)hi);
        }
        return;
    }
    __shared__ float lds[16 * 145];
    int w = blockIdx.x >> 8, co = blockIdx.x & 255;
    const float* src = conv_w + (size_t)(w * 256 + co) * 2304;
    for (int i = threadIdx.x; i < 2304; i += 256) {
        int m = i / 144, tt = i - m * 144;
        lds[m * 145 + tt] = src[i];
    }
    __syncthreads();
    int b = co >> 4, c0 = (co & 15) << 4;
    size_t rbase = (size_t)(b * 16 + w) * 144;
    for (int i = threadIdx.x; i < 2304; i += 256) {
        int t = i >> 4, m = i & 15;
        kt[(rbase + t) * 256 + c0 + m] = (bf16)lds[m * 145 + t];
    }
}

// ======================= async staging primitives =======================
// LDS dest is linear (wave-uniform base + lane*16); the XOR part-swizzle
// LDS(row, s) = global(row, s ^ ((row>>1)&3)) is applied to the per-lane
// GLOBAL source address (involution => same map both sides).
typedef const __attribute__((address_space(1))) unsigned int* gas_t;
typedef __attribute__((address_space(3))) unsigned int* las_t;

__device__ __forceinline__ void async_copy16(const void* g, void* l) {
    __builtin_amdgcn_global_load_lds((gas_t)g, (las_t)l, 16, 0, 0);
}

// ======================= MFMA fragment compute (swizzle f(r) = (r>>1)&3) =======================
__device__ __forceinline__ void mfma_tile_bf16(const bf16* As, const bf16* Bs,
                                               f32x4 acc[4][4]) {
    int lane = threadIdx.x & 63;
    int wave = threadIdx.x >> 6;
    int wm = (wave >> 1) * 64, wn = (wave & 1) * 64;
    int lrow = lane & 15, quad = lane >> 4;
    bf16x8 af[4], bfr[4];
#pragma unroll
    for (int i = 0; i < 4; i++) {
        int r = wm + i * 16 + lrow;
        af[i] = *(const bf16x8*)(As + r * 32 + ((quad ^ ((r >> 1) & 3)) << 3));
        int n = wn + i * 16 + lrow;
        bfr[i] = *(const bf16x8*)(Bs + n * 32 + ((quad ^ ((n >> 1) & 3)) << 3));
    }
#pragma unroll
    for (int i = 0; i < 4; i++)
#pragma unroll
        for (int j = 0; j < 4; j++)
            acc[i][j] = __builtin_amdgcn_mfma_f32_16x16x32_bf16(af[i], bfr[j], acc[i][j], 0, 0, 0);
}

// dual-B variant (64x64 wave tile): load A fragments once, run hi and lo products
__device__ __forceinline__ void mfma_tile_f16_dual(const f16* As, const f16* Bhs,
                                                   const f16* Bls, f32x4 acc[4][4]) {
    int lane = threadIdx.x & 63;
    int wave = threadIdx.x >> 6;
    int wm = (wave >> 1) * 64, wn = (wave & 1) * 64;
    int lrow = lane & 15, quad = lane >> 4;
    f16x8 af[4], bh[4], bl[4];
#pragma unroll
    for (int i = 0; i < 4; i++) {
        int r = wm + i * 16 + lrow;
        af[i] = *(const f16x8*)(As + r * 32 + ((quad ^ ((r >> 1) & 3)) << 3));
        int n = wn + i * 16 + lrow;
        bh[i] = *(const f16x8*)(Bhs + n * 32 + ((quad ^ ((n >> 1) & 3)) << 3));
        bl[i] = *(const f16x8*)(Bls + n * 32 + ((quad ^ ((n >> 1) & 3)) << 3));
    }
#pragma unroll
    for (int i = 0; i < 4; i++)
#pragma unroll
        for (int j = 0; j < 4; j++) {
            acc[i][j] = __builtin_amdgcn_mfma_f32_16x16x32_f16(af[i], bh[j], acc[i][j], 0, 0, 0);
            acc[i][j] = __builtin_amdgcn_mfma_f32_16x16x32_f16(af[i], bl[j], acc[i][j], 0, 0, 0);
        }
}

// big-tile dual-B variant (128x64 wave tile): A x8 frags, B x4+4, 64 MFMAs
__device__ __forceinline__ void mfma_tile_f16_dual8(const f16* As, const f16* Bhs,
                                                    const f16* Bls, f32x4 acc[8][4]) {
    int lane = threadIdx.x & 63;
    int wave = threadIdx.x >> 6;
    int wm = (wave >> 1) * 128, wn = (wave & 1) * 64;
    int lrow = lane & 15, quad = lane >> 4;
    f16x8 af[8], bh[4], bl[4];
#pragma unroll
    for (int i = 0; i < 8; i++) {
        int r = wm + i * 16 + lrow;
        af[i] = *(const f16x8*)(As + r * 32 + ((quad ^ ((r >> 1) & 3)) << 3));
    }
#pragma unroll
    for (int j = 0; j < 4; j++) {
        int n = wn + j * 16 + lrow;
        bh[j] = *(const f16x8*)(Bhs + n * 32 + ((quad ^ ((n >> 1) & 3)) << 3));
        bl[j] = *(const f16x8*)(Bls + n * 32 + ((quad ^ ((n >> 1) & 3)) << 3));
    }
#pragma unroll
    for (int i = 0; i < 8; i++)
#pragma unroll
        for (int j = 0; j < 4; j++) {
            acc[i][j] = __builtin_amdgcn_mfma_f32_16x16x32_f16(af[i], bh[j], acc[i][j], 0, 0, 0);
            acc[i][j] = __builtin_amdgcn_mfma_f32_16x16x32_f16(af[i], bl[j], acc[i][j], 0, 0, 0);
        }
}

// ======================= qkv GEMM (bf16, dbuf + counted vmcnt) =======================
__global__ __launch_bounds__(256) void k_gemm_qkv(const bf16* __restrict__ A,
                                                  const bf16* __restrict__ Bt,
                                                  const float* __restrict__ bias,
                                                  bf16* __restrict__ outb,
                                                  int N, int K) {
    __shared__ __align__(16) bf16 As[2][128 * 32];
    __shared__ __align__(16) bf16 Bs[2][128 * 32];
    int m0 = blockIdx.y * 128, n0 = blockIdx.x * 128;
    int t = threadIdx.x, wave = t >> 6, lane = t & 63;
    int chunk0 = wave * 2, chunk1 = chunk0 + 1;
    int row0 = chunk0 * 16 + (lane >> 2), row1 = row0 + 16;
    int sw = ((lane & 3) ^ ((row0 >> 1) & 3)) << 3;   // (row1>>1)&3 == (row0>>1)&3
    const unsigned short* Ag = (const unsigned short*)A;
    const unsigned short* Bg = (const unsigned short*)Bt;
    size_t a0 = (size_t)(m0 + row0) * K + sw, a1 = (size_t)(m0 + row1) * K + sw;
    size_t b0 = (size_t)(n0 + row0) * K + sw, b1 = (size_t)(n0 + row1) * K + sw;
    f32x4 acc[4][4] = {};
#define STG_QKV(cur, k0)                                        \
    async_copy16(Ag + a0 + (k0), &As[cur][chunk0 * 512]);       \
    async_copy16(Ag + a1 + (k0), &As[cur][chunk1 * 512]);       \
    async_copy16(Bg + b0 + (k0), &Bs[cur][chunk0 * 512]);       \
    async_copy16(Bg + b1 + (k0), &Bs[cur][chunk1 * 512]);
    STG_QKV(0, 0);
    int cur = 0, NT = K >> 5;
#pragma unroll 1
    for (int it = 0; it < NT; it++) {
        if (it < NT - 1) {
            STG_QKV(cur ^ 1, (it + 1) << 5);
            asm volatile("s_waitcnt vmcnt(4)" ::: "memory");
        } else {
            asm volatile("s_waitcnt vmcnt(0)" ::: "memory");
        }
        __builtin_amdgcn_s_barrier();
        mfma_tile_bf16(As[cur], Bs[cur], acc);
        asm volatile("s_waitcnt lgkmcnt(0)" ::: "memory");
        __builtin_amdgcn_s_barrier();
        cur ^= 1;
    }
#undef STG_QKV
    int wm = (wave >> 1) * 64, wn = (wave & 1) * 64;
    int lrow = lane & 15, quad = lane >> 4;
#pragma unroll
    for (int i = 0; i < 4; i++)
#pragma unroll
        for (int j = 0; j < 4; j++) {
            int col = n0 + wn + j * 16 + lrow;
            float bv = bias[col];
#pragma unroll
            for (int rr = 0; rr < 4; rr++) {
                int row = m0 + wm + i * 16 + quad * 4 + rr;
                float v = acc[i][j][rr] + bv;
                if (col < 256) v *= SCALE_Q;
                outb[(size_t)row * N + col] = (bf16)v;
            }
        }
}

// ======================= out-proj GEMM: A fp16 single, B fp16 hi/lo (x64) =======================
__global__ __launch_bounds__(256) void k_gemm_split2(const f16* __restrict__ Ag_,
                                                     const f16* __restrict__ Bhg,
                                                     const f16* __restrict__ Blg,
                                                     const float* __restrict__ bias,
                                                     float* __restrict__ outf,
                                                     int N, int K) {
    __shared__ __align__(16) f16 As[2][128 * 32];
    __shared__ __align__(16) f16 Bh[2][128 * 32];
    __shared__ __align__(16) f16 Bl[2][128 * 32];
    int m0 = blockIdx.y * 128, n0 = blockIdx.x * 128;
    int t = threadIdx.x, wave = t >> 6, lane = t & 63;
    int chunk0 = wave * 2, chunk1 = chunk0 + 1;
    int row0 = chunk0 * 16 + (lane >> 2), row1 = row0 + 16;
    int sw = ((lane & 3) ^ ((row0 >> 1) & 3)) << 3;
    const unsigned short* Au = (const unsigned short*)Ag_;
    const unsigned short* Bhu = (const unsigned short*)Bhg;
    const unsigned short* Blu = (const unsigned short*)Blg;
    size_t a0 = (size_t)(m0 + row0) * K + sw, a1 = (size_t)(m0 + row1) * K + sw;
    size_t b0 = (size_t)(n0 + row0) * K + sw, b1 = (size_t)(n0 + row1) * K + sw;
    f32x4 acc[4][4] = {};
#define STG_SP2(cur, k0)                                        \
    async_copy16(Au + a0 + (k0), &As[cur][chunk0 * 512]);       \
    async_copy16(Au + a1 + (k0), &As[cur][chunk1 * 512]);       \
    async_copy16(Bhu + b0 + (k0), &Bh[cur][chunk0 * 512]);      \
    async_copy16(Bhu + b1 + (k0), &Bh[cur][chunk1 * 512]);      \
    async_copy16(Blu + b0 + (k0), &Bl[cur][chunk0 * 512]);      \
    async_copy16(Blu + b1 + (k0), &Bl[cur][chunk1 * 512]);
    STG_SP2(0, 0);
    int cur = 0, NT = K >> 5;
#pragma unroll 1
    for (int it = 0; it < NT; it++) {
        if (it < NT - 1) {
            STG_SP2(cur ^ 1, (it + 1) << 5);
            asm volatile("s_waitcnt vmcnt(6)" ::: "memory");
        } else {
            asm volatile("s_waitcnt vmcnt(0)" ::: "memory");
        }
        __builtin_amdgcn_s_barrier();
        mfma_tile_f16_dual(As[cur], Bh[cur], Bl[cur], acc);
        asm volatile("s_waitcnt lgkmcnt(0)" ::: "memory");
        __builtin_amdgcn_s_barrier();
        cur ^= 1;
    }
#undef STG_SP2
    int wm = (wave >> 1) * 64, wn = (wave & 1) * 64;
    int lrow = lane & 15, quad = lane >> 4;
#pragma unroll
    for (int i = 0; i < 4; i++)
#pragma unroll
        for (int j = 0; j < 4; j++) {
            int col = n0 + wn + j * 16 + lrow;
            float bv = bias[col];
#pragma unroll
            for (int rr = 0; rr < 4; rr++) {
                int row = m0 + wm + i * 16 + quad * 4 + rr;
                outf[(size_t)row * N + col] = acc[i][j][rr] * KSCALE_INV + bv;
            }
        }
}

// ======================= attention: MFMA flash-style per (d,h) block =======================
__global__ __launch_bounds__(256) void k_attn(const bf16* __restrict__ qkv,
                                              f16* __restrict__ o16) {
    __shared__ bf16 Qs[144 * 32];
    __shared__ bf16 Ks[144 * 32];
    __shared__ f16 Vt[32 * 160];
    __shared__ f16 Ps[4 * 16 * 168];
    int d = blockIdx.x >> 3, h = blockIdx.x & 7;
    const bf16* base = qkv + (size_t)d * 144 * 768 + h * 32;
    int t = threadIdx.x;

    for (int i = t; i < 512; i += 256) Vt[(i >> 4) * 160 + 144 + (i & 15)] = (f16)0.f;
    for (int i = t; i < 576; i += 256) {     // 144 rows * 4 parts
        int row = i >> 2, part = i & 3;
        const bf16* rp = base + (size_t)row * 768;
        uint4 vq = *(const uint4*)(rp + (part << 3));
        uint4 vk = *(const uint4*)(rp + 256 + (part << 3));
        int sw = ((part ^ (row & 3)) << 3);
        *(uint4*)(Qs + row * 32 + sw) = vq;
        *(uint4*)(Ks + row * 32 + sw) = vk;
        bf16x8 v8 = *(const bf16x8*)(rp + 512 + (part << 3));
#pragma unroll
        for (int j = 0; j < 8; j++) Vt[(part * 8 + j) * 160 + row] = (f16)(float)v8[j];
    }
    __syncthreads();

    int wave = t >> 6, lane = t & 63;
    int lrow = lane & 15, quad = lane >> 4;
    f16* Pw = Ps + wave * 16 * 168;
    for (int i = lane; i < 256; i += 64) Pw[(i >> 4) * 168 + 144 + (i & 15)] = (f16)0.f;

    bf16x8 kf[9];
#pragma unroll
    for (int nt = 0; nt < 9; nt++) {
        int r = nt * 16 + lrow;
        kf[nt] = *(const bf16x8*)(Ks + r * 32 + ((quad ^ (r & 3)) << 3));
    }

    for (int mt = wave; mt < 9; mt += 4) {
        int qr = mt * 16 + lrow;
        bf16x8 qf = *(const bf16x8*)(Qs + qr * 32 + ((quad ^ (qr & 3)) << 3));
        f32x4 s[9];
#pragma unroll
        for (int nt = 0; nt < 9; nt++) {
            f32x4 z = {0.f, 0.f, 0.f, 0.f};
            s[nt] = __builtin_amdgcn_mfma_f32_16x16x32_bf16(qf, kf[nt], z, 0, 0, 0);
        }
        f32x4 mx = s[0];
#pragma unroll
        for (int nt = 1; nt < 9; nt++)
#pragma unroll
            for (int c = 0; c < 4; c++) mx[c] = fmaxf(mx[c], s[nt][c]);
#pragma unroll
        for (int off = 1; off < 16; off <<= 1)
#pragma unroll
            for (int c = 0; c < 4; c++) mx[c] = fmaxf(mx[c], __shfl_xor(mx[c], off));
        f32x4 sm = {0.f, 0.f, 0.f, 0.f};
#pragma unroll
        for (int nt = 0; nt < 9; nt++)
#pragma unroll
            for (int c = 0; c < 4; c++) {
                float e = __expf(s[nt][c] - mx[c]);
                s[nt][c] = e;
                sm[c] += e;
            }
#pragma unroll
        for (int off = 1; off < 16; off <<= 1)
#pragma unroll
            for (int c = 0; c < 4; c++) sm[c] += __shfl_xor(sm[c], off);
        f32x4 inv;
#pragma unroll
        for (int c = 0; c < 4; c++) inv[c] = 1.f / sm[c];
#pragma unroll
        for (int nt = 0; nt < 9; nt++)
#pragma unroll
            for (int c = 0; c < 4; c++)
                Pw[(quad * 4 + c) * 168 + nt * 16 + lrow] = (f16)(s[nt][c] * inv[c]);

        f32x4 o0 = {0.f, 0.f, 0.f, 0.f}, o1 = {0.f, 0.f, 0.f, 0.f};
#pragma unroll
        for (int kt = 0; kt < 5; kt++) {
            f16x8 pf = *(const f16x8*)(Pw + lrow * 168 + kt * 32 + quad * 8);
            f16x8 v0 = *(const f16x8*)(Vt + lrow * 160 + kt * 32 + quad * 8);
            f16x8 v1 = *(const f16x8*)(Vt + (16 + lrow) * 160 + kt * 32 + quad * 8);
            o0 = __builtin_amdgcn_mfma_f32_16x16x32_f16(pf, v0, o0, 0, 0, 0);
            o1 = __builtin_amdgcn_mfma_f32_16x16x32_f16(pf, v1, o1, 0, 0, 0);
        }
        size_t ro = ((size_t)d * 144 + mt * 16) * 256 + h * 32;
#pragma unroll
        for (int c = 0; c < 4; c++) {
            size_t rr = ro + (size_t)(quad * 4 + c) * 256;
            o16[rr + lrow] = (f16)o0[c];
            o16[rr + 16 + lrow] = (f16)o1[c];
        }
    }
}

// ======================= SE gate + scale + pack B^T fp16 hi/lo (x64) for conv =======================
__global__ __launch_bounds__(256) void k_se_scale(const float* __restrict__ kern,
                                                  const float* __restrict__ w1,
                                                  const float* __restrict__ b1,
                                                  const float* __restrict__ w2,
                                                  const float* __restrict__ b2,
                                                  f16* __restrict__ kern_hi,
                                                  f16* __restrict__ kern_lo) {
    __shared__ float pooled[256];
    __shared__ float hbuf[16];
    int w = blockIdx.x >> 8, Co = blockIdx.x & 255;
    int ci = threadIdx.x;
    const float* kb = kern + (size_t)(Co * 16 + w) * 9 * 256;
    float v9[9];
    float pv = 0.f;
#pragma unroll
    for (int k9 = 0; k9 < 9; k9++) { v9[k9] = kb[k9 * 256 + ci]; pv += v9[k9]; }
    pooled[ci] = pv * (1.f / 9.f);
    __syncthreads();
    // hidden layer: 16 groups x 16 lanes, wave-parallel dot + shfl reduce
    {
        int hid = ci >> 4, l16 = ci & 15;
        const float* w1p = w1 + (size_t)(w * 16 + hid) * 256;
        float hs = 0.f;
#pragma unroll
        for (int c = l16; c < 256; c += 16) hs += pooled[c] * w1p[c];
        hs += __shfl_xor(hs, 1);
        hs += __shfl_xor(hs, 2);
        hs += __shfl_xor(hs, 4);
        hs += __shfl_xor(hs, 8);
        if (l16 == 0) hbuf[hid] = fmaxf(hs + b1[w * 16 + hid], 0.f);
    }
    __syncthreads();
    const float* w2p = w2 + (size_t)(w * 256 + ci) * 16;
    float ss = b2[w * 256 + ci];
#pragma unroll
    for (int j = 0; j < 16; j++) ss += hbuf[j] * w2p[j];
    float s = (1.f / (1.f + __expf(-ss))) * KSCALE;
    size_t outo = (size_t)(w * 256 + Co) * 2304;
    f16* khi = kern_hi + outo;
    f16* klo = kern_lo + outo;
#pragma unroll
    for (int k9 = 0; k9 < 9; k9++) {
        float f = v9[k9] * s;
        f16 hi = (f16)f;
        khi[k9 * 256 + ci] = hi;
        klo[k9 * 256 + ci] = (f16)(f - (float)hi);
    }
}

// ======================= x -> padded channel-last windows + fused halo zero =======================
// blocks [0,1024): interior fill; blocks [1024,1280): zero the 68-cell halo ring
// (disjoint addresses: interior py,px in [1,16]; halo py/px in {0,17})
__global__ __launch_bounds__(256) void k_fill_xcl(const float* __restrict__ x,
                                                  f16* __restrict__ xcl) {
    int bx = blockIdx.x;
    int ci = threadIdx.x;
    if (bx >= 1024) {
        int wb = bx - 1024;       // w*16 + b, 0..255
        f16* base = xcl + (size_t)wb * 18 * 18 * 256;
#pragma unroll 1
        for (int i = 0; i < 68; i++) {
            int py, px;
            if (i < 18) { py = 0; px = i; }
            else if (i < 36) { py = 17; px = i - 18; }
            else { int k = i - 36; py = 1 + (k >> 1); px = (k & 1) * 17; }
            base[((size_t)py * 18 + px) * 256 + ci] = (f16)0.f;
        }
        return;
    }
    int b = bx >> 6, gy = bx & 63;
    int wrow = gy >> 4, py = gy & 15;
    const float* xp = x + ((size_t)(b * 256 + ci) * 64 + gy) * 64;
    for (int wx = 0; wx < 4; wx++) {
        int w = wrow * 4 + wx;
        size_t o = (((size_t)(w * 16 + b) * 18 + py + 1) * 18 + 1) * 256 + ci;
#pragma unroll
        for (int px = 0; px < 16; px++)
            xcl[o + (size_t)px * 256] = (f16)xp[wx * 16 + px];
    }
}

// ======================= per-window conv: implicit-im2col GEMM, 256x128 block, 128x64 wave tile =======================
// 1D grid 512 with XCD-chunked decode: XCD c owns windows {2c, 2c+1} => B panels +
// A window stay in one XCD's L2. fp32 y output.
__global__ __launch_bounds__(256, 2) void k_conv_gemm(const f16* __restrict__ xcl,
                                                      const f16* __restrict__ kern_hi,
                                                      const f16* __restrict__ kern_lo,
                                                      float* __restrict__ y) {
    __shared__ __align__(16) f16 As[2][256 * 32];
    __shared__ __align__(16) f16 Bh[2][128 * 32];
    __shared__ __align__(16) f16 Bl[2][128 * 32];
    // bijective decode: f = blockIdx.x in [0,512)
    int f = blockIdx.x;
    int xcd = f & 7, i5 = f >> 3;                 // i5 in [0,64)
    int w = xcd * 2 + (i5 >> 5);                  // window 0..15
    int rem = i5 & 31;
    int by = rem >> 1;                            // m-block 0..15 (= batch)
    int n0 = (rem & 1) * 128;                     // n-block
    int m0 = by * 256;
    const unsigned short* xw = (const unsigned short*)(xcl + (size_t)w * 16 * 18 * 18 * 256);
    const unsigned short* Bthu = (const unsigned short*)(kern_hi + (size_t)w * 256 * 2304);
    const unsigned short* Btlu = (const unsigned short*)(kern_lo + (size_t)w * 256 * 2304);
    int t = threadIdx.x, wave = t >> 6, lane = t & 63;
    // swizzle slot is row-dependent only through (row>>1)&3 == (lane>>3)&3 for all our chunks
    int sw = ((lane & 3) ^ ((lane >> 3) & 3)) << 3;
    // A: 16 chunks of 16 rows (1KB each); wave handles chunks wave*4 .. wave*4+3
    size_t aA[4];
#pragma unroll
    for (int c = 0; c < 4; c++) {
        int row = (wave * 4 + c) * 16 + (lane >> 2);   // 0..255
        int py = row >> 4, px = row & 15;
        aA[c] = ((size_t)(by * 18 + py) * 18 + px) * 256 + sw;
    }
    // B: 8 chunks of 16 rows; wave handles chunks wave*2, wave*2+1
    int rb0 = (wave * 2) * 16 + (lane >> 2), rb1 = rb0 + 16;
    size_t bB0 = (size_t)(n0 + rb0) * 2304 + sw;
    size_t bB1 = (size_t)(n0 + rb1) * 2304 + sw;
    f32x4 acc[8][4] = {};
#define STG_CONV(cur, k0)                                                      \
    {                                                                          \
        int k9_ = (k0) >> 8;                                                   \
        int koff_ = ((k9_ / 3) * 18 + (k9_ % 3)) * 256 + ((k0) & 255);         \
        async_copy16(xw + aA[0] + koff_, &As[cur][(wave * 4 + 0) * 512]);      \
        async_copy16(xw + aA[1] + koff_, &As[cur][(wave * 4 + 1) * 512]);      \
        async_copy16(xw + aA[2] + koff_, &As[cur][(wave * 4 + 2) * 512]);      \
        async_copy16(xw + aA[3] + koff_, &As[cur][(wave * 4 + 3) * 512]);      \
        async_copy16(Bthu + bB0 + (k0), &Bh[cur][(wave * 2 + 0) * 512]);       \
        async_copy16(Bthu + bB1 + (k0), &Bh[cur][(wave * 2 + 1) * 512]);       \
        async_copy16(Btlu + bB0 + (k0), &Bl[cur][(wave * 2 + 0) * 512]);       \
        async_copy16(Btlu + bB1 + (k0), &Bl[cur][(wave * 2 + 1) * 512]);       \
    }
    STG_CONV(0, 0);
    int cur = 0;
#pragma unroll 1
    for (int it = 0; it < 72; it++) {
        if (it < 71) {
            STG_CONV(cur ^ 1, (it + 1) << 5);
            asm volatile("s_waitcnt vmcnt(8)" ::: "memory");
        } else {
            asm volatile("s_waitcnt vmcnt(0)" ::: "memory");
        }
        __builtin_amdgcn_s_barrier();
        mfma_tile_f16_dual8(As[cur], Bh[cur], Bl[cur], acc);
        asm volatile("s_waitcnt lgkmcnt(0)" ::: "memory");
        __builtin_amdgcn_s_barrier();
        cur ^= 1;
    }
#undef STG_CONV
    int lrow = lane & 15, quad = lane >> 4;
    int wm = (wave >> 1) * 128, wn = (wave & 1) * 64;
    float* yw = y + (size_t)w * 4096 * 256;
#pragma unroll
    for (int i = 0; i < 8; i++)
#pragma unroll
        for (int j = 0; j < 4; j++) {
            int col = n0 + wn + j * 16 + lrow;
#pragma unroll
            for (int rr = 0; rr < 4; rr++) {
                int row = m0 + wm + i * 16 + quad * 4 + rr;
                yw[(size_t)row * 256 + col] = acc[i][j][rr] * KSCALE_INV;
            }
        }
}

// ======================= layernorm + residual (+window reverse), LDS-transposed coalesced epilogue =======================
__global__ __launch_bounds__(256) void k_ln_res(const float* __restrict__ y,
                                                const float* __restrict__ x,
                                                const float* __restrict__ g,
                                                const float* __restrict__ be,
                                                float* __restrict__ out) {
    __shared__ float vbuf[32 * 257];
    __shared__ float stats[32][2];
    int bx = blockIdx.x;          // (b*64 + gy)*2 + half
    int half = bx & 1, gy = (bx >> 1) & 63, b = bx >> 7;
    int t = threadIdx.x;
    int j = t >> 3, sub = t & 7;          // pixel-in-half, channel-eighth
    int gx = half * 32 + j;
    int w = (gy >> 4) * 4 + (gx >> 4);
    int p = (gy & 15) * 16 + (gx & 15);
    const float* yp = y + ((size_t)w * 4096 + b * 256 + p) * 256 + sub * 32;
    float sum = 0.f, sq = 0.f;
#pragma unroll
    for (int c = 0; c < 32; c++) {
        float v = yp[c];
        vbuf[j * 257 + sub * 32 + c] = v;
        sum += v; sq += v * v;
    }
    sum += __shfl_xor(sum, 1); sq += __shfl_xor(sq, 1);
    sum += __shfl_xor(sum, 2); sq += __shfl_xor(sq, 2);
    sum += __shfl_xor(sum, 4); sq += __shfl_xor(sq, 4);
    if (sub == 0) {
        float mean = sum * (1.f / 256.f);
        float var = sq * (1.f / 256.f) - mean * mean;
        stats[j][0] = mean;
        stats[j][1] = rsqrtf(var + 1e-5f);
    }
    __syncthreads();
    // phase 2
    int wv = t >> 6, lane = t & 63;
    int chp = lane >> 5, lgx = lane & 31;
    float mu = stats[lgx][0], rstd = stats[lgx][1];
    const float* xrow = x + ((size_t)(b * 256) * 64 + gy) * 64 + half * 32 + lgx;
    float* orow = out + ((size_t)(b * 256) * 64 + gy) * 64 + half * 32 + lgx;
#pragma unroll 4
    for (int it = 0; it < 32; it++) {
        int ch = wv * 64 + it * 2 + chp;
        float v = vbuf[lgx * 257 + ch];
        float r = (v - mu) * rstd * g[ch] + be[ch] + xrow[(size_t)ch * 4096];
        orow[(size_t)ch * 4096] = r;
    }
}

// ======================= launch =======================
extern "C" void kernel_launch(void* const* d_in, const int* in_sizes, int n_in,
                              void* d_out, int out_size, void* d_ws, size_t ws_size,
                              hipStream_t stream) {
    const float* x      = (const float*)d_in[0];
    const float* conv_w = (const float*)d_in[1];
    const float* wqkv   = (const float*)d_in[2];
    const float* bqkv   = (const float*)d_in[3];
    const float* wout   = (const float*)d_in[4];
    const float* bout   = (const float*)d_in[5];
    const float* se_w1  = (const float*)d_in[6];
    const float* se_b1  = (const float*)d_in[7];
    const float* se_w2  = (const float*)d_in[8];
    const float* se_b2  = (const float*)d_in[9];
    const float* ln_g   = (const float*)d_in[10];
    const float* ln_b   = (const float*)d_in[11];
    float* out = (float*)d_out;

    // ---- workspace layout (lifetime-overlaid, 147,980,288 B) ----
    char* ws = (char*)d_ws;
    bf16*  kt      = (bf16*)(ws + 0);             // 18,874,368  kt -> o16 -> kern_hi
    f16*   o16     = (f16*)(ws + 0);
    f16*   kern_hi = (f16*)(ws + 0);
    f16*   kern_lo = (f16*)(ws + 18874368);       // 18,874,368
    bf16*  wqkv_t  = (bf16*)(ws + 37748736);      //    393,216
    f16*   wout_h  = (f16*)(ws + 38141952);       //    131,072
    f16*   wout_l  = (f16*)(ws + 38273024);       //    131,072
    f16*   xcl     = (f16*)(ws + 38404096);       // 42,467,328
    bf16*  qkv     = (bf16*)(ws + 80871424);      // 56,623,104  qkv -> kern_f -> y
    float* kern_f  = (float*)(ws + 80871424);     // 37,748,736
    float* y       = (float*)(ws + 80871424);     // 67,108,864

    k_build_kt<<<5120, 256, 0, stream>>>(conv_w, kt, wqkv, wout, wqkv_t, wout_h, wout_l);
    k_gemm_qkv<<<dim3(6, 288), 256, 0, stream>>>(kt, wqkv_t, bqkv, qkv, 768, 256);
    k_attn<<<2048, 256, 0, stream>>>(qkv, o16);
    k_gemm_split2<<<dim3(2, 288), 256, 0, stream>>>(o16, wout_h, wout_l, bout, kern_f, 256, 256);
    k_se_scale<<<4096, 256, 0, stream>>>(kern_f, se_w1, se_b1, se_w2, se_b2, kern_hi, kern_lo);
    k_fill_xcl<<<1280, 256, 0, stream>>>(x, xcl);
    k_conv_gemm<<<512, 256, 0, stream>>>(xcl, kern_hi, kern_lo, y);
    k_ln_res<<<2048, 256, 0, stream>>>(y, x, ln_g, ln_b, out);
}